// Round 10
// baseline (277.119 us; speedup 1.0000x reference)
//
#include <hip/hip_runtime.h>

// ---- problem constants ----
constexpr int N    = 20000;
constexpr int T    = 12;
constexpr int C    = 256;
constexpr int HIDN = 128;
constexpr int OUTD = 12;
constexpr int ER   = 30000;
constexpr int NFT  = 48;               // F*T floats per node
constexpr int EDGE_TOT = 5 * ER;       // 150000
constexpr int CAP      = 32;           // combined bucket capacity (mean 7.5 edges/node)
constexpr int EB       = 586;          // edge blocks = ceil(150000/256)

// workspace layout (4-byte units); deg+cnt+Mv contiguous -> ONE memset
constexpr int WS_DEG    = 0;          // [100000] float
constexpr int WS_CNT    = 100000;     // [20000] int
constexpr int WS_MV     = 120000;     // [10*C + T] float (atomically accumulated)
constexpr int WS_ZEND   = 122576;     // memset end (floats)
constexpr int WS_WP     = 122576;     // 32768 bf16 = 16384 floats (W1 B-frags)
constexpr int WS_W2T    = 138960;     // [OUTD*HIDN] float
constexpr int WS_XV     = 140496;     // [N*48] float aggregated features
constexpr int WS_BUCKET = 1100496;    // [N*CAP] int2 (src, coef-bits), 8B-aligned

constexpr float LOG2E = 1.4426950408889634f;

typedef __attribute__((ext_vector_type(8))) short short8;
typedef __attribute__((ext_vector_type(4))) float floatx4;

#if __has_builtin(__builtin_amdgcn_exp2f)
#define EXP2(x) __builtin_amdgcn_exp2f(x)
#else
#define EXP2(x) exp2f(x)
#endif

__device__ __forceinline__ short f2bf(float f) {   // RNE float->bf16
  unsigned u = __float_as_uint(f);
  u = u + 0x7fffu + ((u >> 16) & 1u);
  return (short)(u >> 16);
}

__device__ __forceinline__ void pick_region(
    int r,
    const int* e0, const int* e1, const int* e2, const int* e3, const int* e4,
    const float* a0, const float* a1, const float* a2, const float* a3, const float* a4,
    const int*& ei, const float*& ea) {
  switch (r) {
    case 0: ei = e0; ea = a0; break;
    case 1: ei = e1; ea = a1; break;
    case 2: ei = e2; ea = a2; break;
    case 3: ei = e3; ea = a3; break;
    default: ei = e4; ea = a4; break;
  }
}

// 1) prep + degree pass (independent work split by blockIdx):
//    b<16      : weight-collapse PARTIALS -> atomicAdd Mv (z pre-scaled log2e, h 2*log2e)
//    b==16     : softmax(att)
//    17<=b<152 : W1 -> bf16 MFMA-B frags; W2 -> W2t
//    b>=152    : deg[rn] += w
__global__ void k_prep_deg(
    const float* __restrict__ Wc_z, const float* __restrict__ bc_z,
    const float* __restrict__ Wl_z, const float* __restrict__ bl_z,
    const float* __restrict__ Wc_h, const float* __restrict__ bc_h,
    const float* __restrict__ Wl_h, const float* __restrict__ bl_h,
    const float* __restrict__ att, const float* __restrict__ W1,
    const float* __restrict__ W2,
    const int* __restrict__ e0, const int* __restrict__ e1,
    const int* __restrict__ e2, const int* __restrict__ e3,
    const int* __restrict__ e4,
    const float* __restrict__ a0, const float* __restrict__ a1,
    const float* __restrict__ a2, const float* __restrict__ a3,
    const float* __restrict__ a4,
    float* __restrict__ Mv, short* __restrict__ Wp, float* __restrict__ W2t,
    float* __restrict__ deg) {
  int b = blockIdx.x, tid = threadIdx.x;
  if (b < 16) {
    int g  = b >> 3;
    int ch = b & 7;
    int k  = tid;
    const float* Wc = g ? Wc_h : Wc_z;
    const float* bc = g ? bc_h : bc_z;
    const float* Wl = g ? Wl_h : Wl_z;
    const float* bl = g ? bl_h : bl_z;
    float scale = g ? 2.0f * LOG2E : LOG2E;
    float m0 = 0.f, m1 = 0.f, m2 = 0.f, m3 = 0.f;
    float v = (ch == 0) ? bl[k] : 0.0f;
    int c0 = ch * 32;
    for (int c = c0; c < c0 + 32; c++) {
      float wl = Wl[c * C + k];
      m0 = fmaf(Wc[0 * C + c], wl, m0);
      m1 = fmaf(Wc[1 * C + c], wl, m1);
      m2 = fmaf(Wc[2 * C + c], wl, m2);
      m3 = fmaf(Wc[3 * C + c], wl, m3);
      v  = fmaf(bc[c], wl, v);
    }
    float* o = Mv + g * (5 * C);
    atomicAdd(&o[0 * C + k], scale * m0);
    atomicAdd(&o[1 * C + k], scale * m1);
    atomicAdd(&o[2 * C + k], scale * m2);
    atomicAdd(&o[3 * C + k], scale * m3);
    atomicAdd(&o[4 * C + k], scale * v);
    return;
  }
  if (b == 16) {
    if (tid < T) {
      float amax = -3.0e38f;
      for (int t = 0; t < T; t++) amax = fmaxf(amax, att[t]);
      float s = 0.f;
      for (int t = 0; t < T; t++) s += __expf(att[t] - amax);
      Mv[10 * C + tid] = __expf(att[tid] - amax) / s;
    }
    return;
  }
  if (b < 152) {
    int idx = (b - 17) * 256 + tid;
    if (idx < 32768) {
      int j    = idx & 7;
      int lane = (idx >> 3) & 63;
      int ch   = (idx >> 9) & 7;
      int kt   = idx >> 12;
      int cin  = ch * 32 + (lane >> 4) * 8 + j;   // K index
      int kout = kt * 16 + (lane & 15);           // N index
      Wp[idx] = f2bf(W1[cin * HIDN + kout]);
    } else if (idx < 32768 + 1536) {
      int r = idx - 32768;
      int o = r >> 7, k = r & 127;
      W2t[r] = W2[k * OUTD + o];
    }
    return;
  }
  int i = (b - 152) * 256 + tid;
  if (i >= EDGE_TOT) return;
  int r = i / ER;
  int e = i - r * ER;
  const int* ei; const float* ea;
  pick_region(r, e0, e1, e2, e3, e4, a0, a1, a2, a3, a4, ei, ea);
  atomicAdd(&deg[r * N + ei[ER + e]], ea[e]);
}

// 2) fill pass (deg final): combined per-node bucket gets (src, coef)
__global__ void k_fill(const int* __restrict__ e0, const int* __restrict__ e1,
                       const int* __restrict__ e2, const int* __restrict__ e3,
                       const int* __restrict__ e4,
                       const float* __restrict__ a0, const float* __restrict__ a1,
                       const float* __restrict__ a2, const float* __restrict__ a3,
                       const float* __restrict__ a4,
                       const float* __restrict__ deg, int* __restrict__ cnt,
                       int2* __restrict__ bucket) {
  int i = blockIdx.x * blockDim.x + threadIdx.x;
  if (i >= EDGE_TOT) return;
  int r = i / ER;
  int e = i - r * ER;
  const int* ei; const float* ea;
  pick_region(r, e0, e1, e2, e3, e4, a0, a1, a2, a3, a4, ei, ea);
  int src = ei[e];
  int dst = ei[ER + e];
  float cf = rsqrtf(deg[r * N + src] + 1.0f) * ea[e] * rsqrtf(deg[r * N + dst] + 1.0f);
  int slot = atomicAdd(&cnt[dst], 1);
  if (slot < CAP) bucket[dst * CAP + slot] = make_int2(src, __float_as_int(cf));
}

// 3) gather: one wave per node, lane = feature q (48/64 active).
//    Bucket row preloaded with ONE lane-indexed int2 load; per-edge (src,coef)
//    broadcast via dynamic __shfl (ds_bpermute) -- no global-load chain.
__global__ __launch_bounds__(256) void k_gather(
    const float* __restrict__ x, const float* __restrict__ deg,
    const int* __restrict__ cnt, const int2* __restrict__ bucket,
    float* __restrict__ xv) {
  int wave = threadIdx.x >> 6, lane = threadIdx.x & 63;
  int n = blockIdx.x * 4 + wave;
  int q = lane < NFT ? lane : NFT - 1;   // clamp idle lanes
  float s = 0.f;
#pragma unroll
  for (int r = 0; r < 5; r++) s += 1.0f / (deg[r * N + n] + 1.0f);
  float facc = s * x[n * NFT + q];
  int cv = cnt[n];
  if (cv > CAP) cv = CAP;
  int2 mreg = bucket[n * CAP + (lane & (CAP - 1))];   // slots in lanes 0..31
  for (int j = 0; j < cv; j++) {
    int   src = __shfl(mreg.x, j);
    float cf  = __int_as_float(__shfl(mreg.y, j));
    facc = fmaf(cf, x[src * NFT + q], facc);
  }
  if (lane < NFT) xv[n * NFT + q] = facc;
}

// 4) fused gates + attention pooling + MLP.  Block = 16 nodes, 4 waves.
//    Gates phase: wave w owns HALF (w&1) of nodes (w>>1)*8..+8, lane owns 2
//    channels -> halved constant arrays (~64 VGPR vs R7's 96) for occupancy.
//    Writes fp32 h to global + bf16 relu(h) to LDS; one barrier; 16 MFMAs/wave
//    layer-1 + tiny layer-2 (R8-verified tail).
__global__ __launch_bounds__(256, 6) void k_gates_mlp(
    const float* __restrict__ xv, const float* __restrict__ Mv,
    const short* __restrict__ Wp, const float* __restrict__ b1,
    const float* __restrict__ W2t, const float* __restrict__ b2,
    float* __restrict__ y_out, float* __restrict__ h_out) {
  __shared__ short hs[16][264];       // bf16 relu(h), pad 256->264
  __shared__ float y1s[16][132];      // fp32 layer-1 out, pad 128->132
  int tid = threadIdx.x;
  int wave = tid >> 6, lane = tid & 63;
  int quad = lane >> 4, col = lane & 15;
  int n0 = blockIdx.x * 16;

  // ---- gates phase: half = wave&1, nodes (wave>>1)*8 .. +8, 2 ch/lane ----
  int half = wave & 1;
  int nb   = (wave >> 1) * 8;
  int c0 = half * 128 + (lane << 1);
  const float* Mz = Mv;               // pre-scaled by log2e
  const float* Mh = Mv + 5 * C;       // pre-scaled by 2*log2e
  float mz[4][2], mh[4][2], vz[2], vh[2];
#pragma unroll
  for (int f = 0; f < 4; f++) {
    float2 t1 = *(const float2*)(Mz + f * C + c0);
    mz[f][0] = t1.x; mz[f][1] = t1.y;
    float2 t2 = *(const float2*)(Mh + f * C + c0);
    mh[f][0] = t2.x; mh[f][1] = t2.y;
  }
  {
    float2 t1 = *(const float2*)(Mz + 4 * C + c0);
    vz[0] = t1.x; vz[1] = t1.y;
    float2 t2 = *(const float2*)(Mh + 4 * C + c0);
    vh[0] = t2.x; vh[1] = t2.y;
  }

#pragma unroll
  for (int nl = 0; nl < 8; nl++) {
    int rl = nb + nl;                  // local node 0..15
    int n = n0 + rl;
    const float* xr = xv + n * NFT;
    float acc[2] = {0.f, 0.f};
#pragma unroll
    for (int tb = 0; tb < 3; tb++) {
      float4 xf0 = *(const float4*)(xr + 0 * T + tb * 4);
      float4 xf1 = *(const float4*)(xr + 1 * T + tb * 4);
      float4 xf2 = *(const float4*)(xr + 2 * T + tb * 4);
      float4 xf3 = *(const float4*)(xr + 3 * T + tb * 4);
      float xs0[4] = {xf0.x, xf0.y, xf0.z, xf0.w};
      float xs1[4] = {xf1.x, xf1.y, xf1.z, xf1.w};
      float xs2[4] = {xf2.x, xf2.y, xf2.z, xf2.w};
      float xs3[4] = {xf3.x, xf3.y, xf3.z, xf3.w};
#pragma unroll
      for (int tt = 0; tt < 4; tt++) {
        int t = tb * 4 + tt;
        float p = Mv[10 * C + t];      // uniform address -> s_load
        float x0 = xs0[tt], x1 = xs1[tt], x2 = xs2[tt], x3 = xs3[tt];
#pragma unroll
        for (int j = 0; j < 2; j++) {
          float az = fmaf(mz[0][j], x0, fmaf(mz[1][j], x1, fmaf(mz[2][j], x2, fmaf(mz[3][j], x3, vz[j]))));
          float ah = fmaf(mh[0][j], x0, fmaf(mh[1][j], x1, fmaf(mh[2][j], x2, fmaf(mh[3][j], x3, vh[j]))));
          float e1 = EXP2(az);                        // e^{az_true}
          float e2 = EXP2(ah);                        // e^{2*ah_true}
          float den = (1.0f + e1) * (1.0f + e2);
          float rD  = __builtin_amdgcn_rcpf(den);
          float pn  = fmaf(p, e2, -p);                // p*(e2-1)
          acc[j] = fmaf(pn, rD, acc[j]);
        }
      }
    }
    float2 o = {acc[0], acc[1]};
    *(float2*)(h_out + n * C + c0) = o;               // required fp32 output
    unsigned pk = (unsigned short)f2bf(fmaxf(acc[0], 0.f)) |
                  ((unsigned)(unsigned short)f2bf(fmaxf(acc[1], 0.f)) << 16);
    *(unsigned*)&hs[rl][c0] = pk;                     // bf16 relu(h) -> LDS
  }
  __syncthreads();

  // ---- layer 1: 16 MFMAs per wave (kt = wave*2, wave*2+1) ----
  floatx4 acc2[2];
  acc2[0] = {0.f, 0.f, 0.f, 0.f};
  acc2[1] = {0.f, 0.f, 0.f, 0.f};
#pragma unroll
  for (int ch = 0; ch < 8; ch++) {
    short8 a = *(const short8*)&hs[col][ch * 32 + quad * 8];
#pragma unroll
    for (int kk = 0; kk < 2; kk++) {
      short8 b = ((const short8*)Wp)[((wave * 2 + kk) * 8 + ch) * 64 + lane];
      acc2[kk] = __builtin_amdgcn_mfma_f32_16x16x32_bf16(a, b, acc2[kk], 0, 0, 0);
    }
  }
#pragma unroll
  for (int kk = 0; kk < 2; kk++) {
    int kt = wave * 2 + kk;
    float bias = b1[kt * 16 + col];
#pragma unroll
    for (int r = 0; r < 4; r++)
      y1s[quad * 4 + r][kt * 16 + col] = fmaxf(acc2[kk][r] + bias, 0.f);
  }
  __syncthreads();

  // ---- layer 2: 16 nodes x 12 outputs = 192 threads ----
  if (tid < 16 * OUTD) {
    int nl = tid / OUTD, o = tid - nl * OUTD;
    float sacc = b2[o];
    const float* yr = &y1s[nl][0];
    const float* wr = W2t + o * HIDN;
#pragma unroll 8
    for (int k4 = 0; k4 < 32; k4++) {
      float4 yv = *(const float4*)(yr + 4 * k4);
      float4 wv = *(const float4*)(wr + 4 * k4);
      sacc = fmaf(yv.x, wv.x, fmaf(yv.y, wv.y, fmaf(yv.z, wv.z, fmaf(yv.w, wv.w, sacc))));
    }
    y_out[(n0 + nl) * OUTD + o] = sacc;
  }
}

extern "C" void kernel_launch(void* const* d_in, const int* in_sizes, int n_in,
                              void* d_out, int out_size, void* d_ws, size_t ws_size,
                              hipStream_t stream) {
  const float* x   = (const float*)d_in[0];
  // d_in[1] full-graph edge_index: provably unused
  const int* eIA = (const int*)d_in[2];
  const int* eKS = (const int*)d_in[3];
  const int* eKY = (const int*)d_in[4];
  const int* eOH = (const int*)d_in[5];
  const int* eWI = (const int*)d_in[6];
  const float* aIA = (const float*)d_in[7];
  const float* aKS = (const float*)d_in[8];
  const float* aKY = (const float*)d_in[9];
  const float* aOH = (const float*)d_in[10];
  const float* aWI = (const float*)d_in[11];
  const float* Wc_z = (const float*)d_in[12];
  const float* bc_z = (const float*)d_in[13];
  const float* Wl_z = (const float*)d_in[14];
  const float* bl_z = (const float*)d_in[15];
  // r-gate params (16..19) cannot influence the output (H=0)
  const float* Wc_h = (const float*)d_in[20];
  const float* bc_h = (const float*)d_in[21];
  const float* Wl_h = (const float*)d_in[22];
  const float* bl_h = (const float*)d_in[23];
  const float* att  = (const float*)d_in[24];
  const float* W1   = (const float*)d_in[25];
  const float* b1   = (const float*)d_in[26];
  const float* W2   = (const float*)d_in[27];
  const float* b2   = (const float*)d_in[28];

  float* ws     = (float*)d_ws;
  float* deg    = ws + WS_DEG;
  int*   cnt    = (int*)(ws + WS_CNT);
  float* Mv     = ws + WS_MV;
  short* Wp     = (short*)(ws + WS_WP);
  float* W2t    = ws + WS_W2T;
  float* xvb    = ws + WS_XV;
  int2*  bucket = (int2*)(ws + WS_BUCKET);

  float* y_out = (float*)d_out;            // [N,12]
  float* h_out = y_out + N * OUTD;         // [N,256]

  hipMemsetAsync(deg, 0, WS_ZEND * sizeof(float), stream);  // deg + cnt + Mv

  k_prep_deg<<<152 + EB, 256, 0, stream>>>(Wc_z, bc_z, Wl_z, bl_z,
                                           Wc_h, bc_h, Wl_h, bl_h,
                                           att, W1, W2,
                                           eIA, eKS, eKY, eOH, eWI,
                                           aIA, aKS, aKY, aOH, aWI,
                                           Mv, Wp, W2t, deg);
  k_fill<<<EB, 256, 0, stream>>>(eIA, eKS, eKY, eOH, eWI,
                                 aIA, aKS, aKY, aOH, aWI,
                                 deg, cnt, bucket);
  k_gather<<<N / 4, 256, 0, stream>>>(x, deg, cnt, bucket, xvb);
  k_gates_mlp<<<N / 16, 256, 0, stream>>>(xvb, Mv, Wp, b1, W2t, b2, y_out, h_out);
}

// Round 11
// 198.262 us; speedup vs baseline: 1.3977x; 1.3977x over previous
//
#include <hip/hip_runtime.h>

// ---- problem constants ----
constexpr int N    = 20000;
constexpr int T    = 12;
constexpr int C    = 256;
constexpr int HIDN = 128;
constexpr int OUTD = 12;
constexpr int ER   = 30000;
constexpr int NFT  = 48;               // F*T floats per node
constexpr int EDGE_TOT = 5 * ER;       // 150000
constexpr int CAP      = 32;           // combined bucket capacity (mean 7.5 edges/node)
constexpr int EB       = 586;          // edge blocks = ceil(150000/256)

// workspace layout (4-byte units); deg+cnt+Mv contiguous -> ONE memset
constexpr int WS_DEG    = 0;          // [100000] float
constexpr int WS_CNT    = 100000;     // [20000] int
constexpr int WS_MV     = 120000;     // [10*C + T] float (atomically accumulated)
constexpr int WS_ZEND   = 122576;     // memset end (floats)
constexpr int WS_WP     = 122576;     // 32768 bf16 = 16384 floats (W1 B-frags)
constexpr int WS_W2T    = 138960;     // [OUTD*HIDN] float
constexpr int WS_XV     = 140496;     // [N*48] float aggregated features
constexpr int WS_BUCKET = 1100496;    // [N*CAP] int2 (src, coef-bits), 8B-aligned

constexpr float LOG2E = 1.4426950408889634f;

typedef __attribute__((ext_vector_type(8))) short short8;
typedef __attribute__((ext_vector_type(4))) float floatx4;

#if __has_builtin(__builtin_amdgcn_exp2f)
#define EXP2(x) __builtin_amdgcn_exp2f(x)
#else
#define EXP2(x) exp2f(x)
#endif

__device__ __forceinline__ short f2bf(float f) {   // RNE float->bf16
  unsigned u = __float_as_uint(f);
  u = u + 0x7fffu + ((u >> 16) & 1u);
  return (short)(u >> 16);
}

__device__ __forceinline__ void pick_region(
    int r,
    const int* e0, const int* e1, const int* e2, const int* e3, const int* e4,
    const float* a0, const float* a1, const float* a2, const float* a3, const float* a4,
    const int*& ei, const float*& ea) {
  switch (r) {
    case 0: ei = e0; ea = a0; break;
    case 1: ei = e1; ea = a1; break;
    case 2: ei = e2; ea = a2; break;
    case 3: ei = e3; ea = a3; break;
    default: ei = e4; ea = a4; break;
  }
}

// 1) prep + degree pass (independent work split by blockIdx):
//    b<16      : weight-collapse PARTIALS -> atomicAdd Mv (z pre-scaled log2e, h 2*log2e)
//    b==16     : softmax(att)
//    17<=b<152 : W1 -> bf16 MFMA-B frags; W2 -> W2t
//    b>=152    : deg[rn] += w
__global__ void k_prep_deg(
    const float* __restrict__ Wc_z, const float* __restrict__ bc_z,
    const float* __restrict__ Wl_z, const float* __restrict__ bl_z,
    const float* __restrict__ Wc_h, const float* __restrict__ bc_h,
    const float* __restrict__ Wl_h, const float* __restrict__ bl_h,
    const float* __restrict__ att, const float* __restrict__ W1,
    const float* __restrict__ W2,
    const int* __restrict__ e0, const int* __restrict__ e1,
    const int* __restrict__ e2, const int* __restrict__ e3,
    const int* __restrict__ e4,
    const float* __restrict__ a0, const float* __restrict__ a1,
    const float* __restrict__ a2, const float* __restrict__ a3,
    const float* __restrict__ a4,
    float* __restrict__ Mv, short* __restrict__ Wp, float* __restrict__ W2t,
    float* __restrict__ deg) {
  int b = blockIdx.x, tid = threadIdx.x;
  if (b < 16) {
    int g  = b >> 3;
    int ch = b & 7;
    int k  = tid;
    const float* Wc = g ? Wc_h : Wc_z;
    const float* bc = g ? bc_h : bc_z;
    const float* Wl = g ? Wl_h : Wl_z;
    const float* bl = g ? bl_h : bl_z;
    float scale = g ? 2.0f * LOG2E : LOG2E;
    float m0 = 0.f, m1 = 0.f, m2 = 0.f, m3 = 0.f;
    float v = (ch == 0) ? bl[k] : 0.0f;
    int c0 = ch * 32;
    for (int c = c0; c < c0 + 32; c++) {
      float wl = Wl[c * C + k];
      m0 = fmaf(Wc[0 * C + c], wl, m0);
      m1 = fmaf(Wc[1 * C + c], wl, m1);
      m2 = fmaf(Wc[2 * C + c], wl, m2);
      m3 = fmaf(Wc[3 * C + c], wl, m3);
      v  = fmaf(bc[c], wl, v);
    }
    float* o = Mv + g * (5 * C);
    atomicAdd(&o[0 * C + k], scale * m0);
    atomicAdd(&o[1 * C + k], scale * m1);
    atomicAdd(&o[2 * C + k], scale * m2);
    atomicAdd(&o[3 * C + k], scale * m3);
    atomicAdd(&o[4 * C + k], scale * v);
    return;
  }
  if (b == 16) {
    if (tid < T) {
      float amax = -3.0e38f;
      for (int t = 0; t < T; t++) amax = fmaxf(amax, att[t]);
      float s = 0.f;
      for (int t = 0; t < T; t++) s += __expf(att[t] - amax);
      Mv[10 * C + tid] = __expf(att[tid] - amax) / s;
    }
    return;
  }
  if (b < 152) {
    int idx = (b - 17) * 256 + tid;
    if (idx < 32768) {
      int j    = idx & 7;
      int lane = (idx >> 3) & 63;
      int ch   = (idx >> 9) & 7;
      int kt   = idx >> 12;
      int cin  = ch * 32 + (lane >> 4) * 8 + j;   // K index
      int kout = kt * 16 + (lane & 15);           // N index
      Wp[idx] = f2bf(W1[cin * HIDN + kout]);
    } else if (idx < 32768 + 1536) {
      int r = idx - 32768;
      int o = r >> 7, k = r & 127;
      W2t[r] = W2[k * OUTD + o];
    }
    return;
  }
  int i = (b - 152) * 256 + tid;
  if (i >= EDGE_TOT) return;
  int r = i / ER;
  int e = i - r * ER;
  const int* ei; const float* ea;
  pick_region(r, e0, e1, e2, e3, e4, a0, a1, a2, a3, a4, ei, ea);
  atomicAdd(&deg[r * N + ei[ER + e]], ea[e]);
}

// 2) fill pass (deg final): combined per-node bucket gets (src, coef)
__global__ void k_fill(const int* __restrict__ e0, const int* __restrict__ e1,
                       const int* __restrict__ e2, const int* __restrict__ e3,
                       const int* __restrict__ e4,
                       const float* __restrict__ a0, const float* __restrict__ a1,
                       const float* __restrict__ a2, const float* __restrict__ a3,
                       const float* __restrict__ a4,
                       const float* __restrict__ deg, int* __restrict__ cnt,
                       int2* __restrict__ bucket) {
  int i = blockIdx.x * blockDim.x + threadIdx.x;
  if (i >= EDGE_TOT) return;
  int r = i / ER;
  int e = i - r * ER;
  const int* ei; const float* ea;
  pick_region(r, e0, e1, e2, e3, e4, a0, a1, a2, a3, a4, ei, ea);
  int src = ei[e];
  int dst = ei[ER + e];
  float cf = rsqrtf(deg[r * N + src] + 1.0f) * ea[e] * rsqrtf(deg[r * N + dst] + 1.0f);
  int slot = atomicAdd(&cnt[dst], 1);
  if (slot < CAP) bucket[dst * CAP + slot] = make_int2(src, __float_as_int(cf));
}

// 3) gather: one wave per node, lane = feature q (48/64 active).
//    Bucket row preloaded with ONE lane-indexed int2 load; per-edge (src,coef)
//    broadcast via dynamic __shfl (ds_bpermute) -- no global-load chain.
__global__ __launch_bounds__(256) void k_gather(
    const float* __restrict__ x, const float* __restrict__ deg,
    const int* __restrict__ cnt, const int2* __restrict__ bucket,
    float* __restrict__ xv) {
  int wave = threadIdx.x >> 6, lane = threadIdx.x & 63;
  int n = blockIdx.x * 4 + wave;
  int q = lane < NFT ? lane : NFT - 1;   // clamp idle lanes
  float s = 0.f;
#pragma unroll
  for (int r = 0; r < 5; r++) s += 1.0f / (deg[r * N + n] + 1.0f);
  float facc = s * x[n * NFT + q];
  int cv = cnt[n];
  if (cv > CAP) cv = CAP;
  int2 mreg = bucket[n * CAP + (lane & (CAP - 1))];   // slots in lanes 0..31
  for (int j = 0; j < cv; j++) {
    int   src = __shfl(mreg.x, j);
    float cf  = __int_as_float(__shfl(mreg.y, j));
    facc = fmaf(cf, x[src * NFT + q], facc);
  }
  if (lane < NFT) xv[n * NFT + q] = facc;
}

// 4) fused gates + attention pooling + MLP.  Block = 16 nodes, 4 waves.
//    Gates phase: wave w owns HALF (w&1) of nodes (w>>1)*8..+8, lane owns 2
//    channels -> halved constant arrays keep VGPR ~64 NATURALLY (no forced
//    launch bound -- R10's (256,6) caused VGPR=40 + catastrophic scratch spill:
//    WRITE_SIZE 275 MB).  fp32 h to global + bf16 relu(h) to LDS; one barrier;
//    16 MFMAs/wave layer-1 + tiny layer-2 (R8-verified tail).
__global__ __launch_bounds__(256) void k_gates_mlp(
    const float* __restrict__ xv, const float* __restrict__ Mv,
    const short* __restrict__ Wp, const float* __restrict__ b1,
    const float* __restrict__ W2t, const float* __restrict__ b2,
    float* __restrict__ y_out, float* __restrict__ h_out) {
  __shared__ short hs[16][264];       // bf16 relu(h), pad 256->264
  __shared__ float y1s[16][132];      // fp32 layer-1 out, pad 128->132
  int tid = threadIdx.x;
  int wave = tid >> 6, lane = tid & 63;
  int quad = lane >> 4, col = lane & 15;
  int n0 = blockIdx.x * 16;

  // ---- gates phase: half = wave&1, nodes (wave>>1)*8 .. +8, 2 ch/lane ----
  int half = wave & 1;
  int nb   = (wave >> 1) * 8;
  int c0 = half * 128 + (lane << 1);
  const float* Mz = Mv;               // pre-scaled by log2e
  const float* Mh = Mv + 5 * C;       // pre-scaled by 2*log2e
  float mz[4][2], mh[4][2], vz[2], vh[2];
#pragma unroll
  for (int f = 0; f < 4; f++) {
    float2 t1 = *(const float2*)(Mz + f * C + c0);
    mz[f][0] = t1.x; mz[f][1] = t1.y;
    float2 t2 = *(const float2*)(Mh + f * C + c0);
    mh[f][0] = t2.x; mh[f][1] = t2.y;
  }
  {
    float2 t1 = *(const float2*)(Mz + 4 * C + c0);
    vz[0] = t1.x; vz[1] = t1.y;
    float2 t2 = *(const float2*)(Mh + 4 * C + c0);
    vh[0] = t2.x; vh[1] = t2.y;
  }

#pragma unroll
  for (int nl = 0; nl < 8; nl++) {
    int rl = nb + nl;                  // local node 0..15
    int n = n0 + rl;
    const float* xr = xv + n * NFT;
    float acc[2] = {0.f, 0.f};
#pragma unroll
    for (int tb = 0; tb < 3; tb++) {
      float4 xf0 = *(const float4*)(xr + 0 * T + tb * 4);
      float4 xf1 = *(const float4*)(xr + 1 * T + tb * 4);
      float4 xf2 = *(const float4*)(xr + 2 * T + tb * 4);
      float4 xf3 = *(const float4*)(xr + 3 * T + tb * 4);
      float xs0[4] = {xf0.x, xf0.y, xf0.z, xf0.w};
      float xs1[4] = {xf1.x, xf1.y, xf1.z, xf1.w};
      float xs2[4] = {xf2.x, xf2.y, xf2.z, xf2.w};
      float xs3[4] = {xf3.x, xf3.y, xf3.z, xf3.w};
#pragma unroll
      for (int tt = 0; tt < 4; tt++) {
        int t = tb * 4 + tt;
        float p = Mv[10 * C + t];      // uniform address -> s_load
        float x0 = xs0[tt], x1 = xs1[tt], x2 = xs2[tt], x3 = xs3[tt];
#pragma unroll
        for (int j = 0; j < 2; j++) {
          float az = fmaf(mz[0][j], x0, fmaf(mz[1][j], x1, fmaf(mz[2][j], x2, fmaf(mz[3][j], x3, vz[j]))));
          float ah = fmaf(mh[0][j], x0, fmaf(mh[1][j], x1, fmaf(mh[2][j], x2, fmaf(mh[3][j], x3, vh[j]))));
          float e1 = EXP2(az);                        // e^{az_true}
          float e2 = EXP2(ah);                        // e^{2*ah_true}
          float den = (1.0f + e1) * (1.0f + e2);
          float rD  = __builtin_amdgcn_rcpf(den);
          float pn  = fmaf(p, e2, -p);                // p*(e2-1)
          acc[j] = fmaf(pn, rD, acc[j]);
        }
      }
    }
    float2 o = {acc[0], acc[1]};
    *(float2*)(h_out + n * C + c0) = o;               // required fp32 output
    unsigned pk = (unsigned short)f2bf(fmaxf(acc[0], 0.f)) |
                  ((unsigned)(unsigned short)f2bf(fmaxf(acc[1], 0.f)) << 16);
    *(unsigned*)&hs[rl][c0] = pk;                     // bf16 relu(h) -> LDS
  }
  __syncthreads();

  // ---- layer 1: 16 MFMAs per wave (kt = wave*2, wave*2+1) ----
  floatx4 acc2[2];
  acc2[0] = {0.f, 0.f, 0.f, 0.f};
  acc2[1] = {0.f, 0.f, 0.f, 0.f};
#pragma unroll
  for (int ch = 0; ch < 8; ch++) {
    short8 a = *(const short8*)&hs[col][ch * 32 + quad * 8];
#pragma unroll
    for (int kk = 0; kk < 2; kk++) {
      short8 b = ((const short8*)Wp)[((wave * 2 + kk) * 8 + ch) * 64 + lane];
      acc2[kk] = __builtin_amdgcn_mfma_f32_16x16x32_bf16(a, b, acc2[kk], 0, 0, 0);
    }
  }
#pragma unroll
  for (int kk = 0; kk < 2; kk++) {
    int kt = wave * 2 + kk;
    float bias = b1[kt * 16 + col];
#pragma unroll
    for (int r = 0; r < 4; r++)
      y1s[quad * 4 + r][kt * 16 + col] = fmaxf(acc2[kk][r] + bias, 0.f);
  }
  __syncthreads();

  // ---- layer 2: 16 nodes x 12 outputs = 192 threads ----
  if (tid < 16 * OUTD) {
    int nl = tid / OUTD, o = tid - nl * OUTD;
    float sacc = b2[o];
    const float* yr = &y1s[nl][0];
    const float* wr = W2t + o * HIDN;
#pragma unroll 8
    for (int k4 = 0; k4 < 32; k4++) {
      float4 yv = *(const float4*)(yr + 4 * k4);
      float4 wv = *(const float4*)(wr + 4 * k4);
      sacc = fmaf(yv.x, wv.x, fmaf(yv.y, wv.y, fmaf(yv.z, wv.z, fmaf(yv.w, wv.w, sacc))));
    }
    y_out[(n0 + nl) * OUTD + o] = sacc;
  }
}

extern "C" void kernel_launch(void* const* d_in, const int* in_sizes, int n_in,
                              void* d_out, int out_size, void* d_ws, size_t ws_size,
                              hipStream_t stream) {
  const float* x   = (const float*)d_in[0];
  // d_in[1] full-graph edge_index: provably unused
  const int* eIA = (const int*)d_in[2];
  const int* eKS = (const int*)d_in[3];
  const int* eKY = (const int*)d_in[4];
  const int* eOH = (const int*)d_in[5];
  const int* eWI = (const int*)d_in[6];
  const float* aIA = (const float*)d_in[7];
  const float* aKS = (const float*)d_in[8];
  const float* aKY = (const float*)d_in[9];
  const float* aOH = (const float*)d_in[10];
  const float* aWI = (const float*)d_in[11];
  const float* Wc_z = (const float*)d_in[12];
  const float* bc_z = (const float*)d_in[13];
  const float* Wl_z = (const float*)d_in[14];
  const float* bl_z = (const float*)d_in[15];
  // r-gate params (16..19) cannot influence the output (H=0)
  const float* Wc_h = (const float*)d_in[20];
  const float* bc_h = (const float*)d_in[21];
  const float* Wl_h = (const float*)d_in[22];
  const float* bl_h = (const float*)d_in[23];
  const float* att  = (const float*)d_in[24];
  const float* W1   = (const float*)d_in[25];
  const float* b1   = (const float*)d_in[26];
  const float* W2   = (const float*)d_in[27];
  const float* b2   = (const float*)d_in[28];

  float* ws     = (float*)d_ws;
  float* deg    = ws + WS_DEG;
  int*   cnt    = (int*)(ws + WS_CNT);
  float* Mv     = ws + WS_MV;
  short* Wp     = (short*)(ws + WS_WP);
  float* W2t    = ws + WS_W2T;
  float* xvb    = ws + WS_XV;
  int2*  bucket = (int2*)(ws + WS_BUCKET);

  float* y_out = (float*)d_out;            // [N,12]
  float* h_out = y_out + N * OUTD;         // [N,256]

  hipMemsetAsync(deg, 0, WS_ZEND * sizeof(float), stream);  // deg + cnt + Mv

  k_prep_deg<<<152 + EB, 256, 0, stream>>>(Wc_z, bc_z, Wl_z, bl_z,
                                           Wc_h, bc_h, Wl_h, bl_h,
                                           att, W1, W2,
                                           eIA, eKS, eKY, eOH, eWI,
                                           aIA, aKS, aKY, aOH, aWI,
                                           Mv, Wp, W2t, deg);
  k_fill<<<EB, 256, 0, stream>>>(eIA, eKS, eKY, eOH, eWI,
                                 aIA, aKS, aKY, aOH, aWI,
                                 deg, cnt, bucket);
  k_gather<<<N / 4, 256, 0, stream>>>(x, deg, cnt, bucket, xvb);
  k_gates_mlp<<<N / 16, 256, 0, stream>>>(xvb, Mv, Wp, b1, W2t, b2, y_out, h_out);
}

// Round 13
// 188.482 us; speedup vs baseline: 1.4703x; 1.0519x over previous
//
#include <hip/hip_runtime.h>

// ---- problem constants ----
constexpr int N    = 20000;
constexpr int T    = 12;
constexpr int C    = 256;
constexpr int HIDN = 128;
constexpr int OUTD = 12;
constexpr int ER   = 30000;
constexpr int NFT  = 48;               // F*T floats per node
constexpr int EDGE_TOT = 5 * ER;       // 150000
constexpr int CAP      = 32;           // combined bucket capacity (mean 7.5 edges/node)
constexpr int EB       = 586;          // edge blocks = ceil(150000/256)

// workspace layout (4-byte units); deg+cnt+Mv contiguous -> ONE memset
constexpr int WS_DEG    = 0;          // [100000] float
constexpr int WS_CNT    = 100000;     // [20000] int
constexpr int WS_MV     = 120000;     // [10*C + T] float (atomically accumulated)
constexpr int WS_ZEND   = 122576;     // memset end (floats)
constexpr int WS_WP     = 122576;     // 32768 bf16 = 16384 floats (W1 B-frags)
constexpr int WS_W2T    = 138960;     // [OUTD*HIDN] float
constexpr int WS_BUCKET = 140496;     // [N*CAP] int2 (src, coef-bits), 8B-aligned

constexpr float LOG2E = 1.4426950408889634f;

typedef __attribute__((ext_vector_type(8))) short short8;
typedef __attribute__((ext_vector_type(4))) float floatx4;
typedef __attribute__((ext_vector_type(2))) float floatx2;

#if __has_builtin(__builtin_amdgcn_exp2f)
#define EXP2(x) __builtin_amdgcn_exp2f(x)
#else
#define EXP2(x) exp2f(x)
#endif

__device__ __forceinline__ floatx2 pk_fma(floatx2 a, floatx2 b, floatx2 c) {
  floatx2 r;
  r.x = fmaf(a.x, b.x, c.x);
  r.y = fmaf(a.y, b.y, c.y);
  return r;                            // -> v_pk_fma_f32
}

__device__ __forceinline__ short f2bf(float f) {   // RNE float->bf16
  unsigned u = __float_as_uint(f);
  u = u + 0x7fffu + ((u >> 16) & 1u);
  return (short)(u >> 16);
}

__device__ __forceinline__ void pick_region(
    int r,
    const int* e0, const int* e1, const int* e2, const int* e3, const int* e4,
    const float* a0, const float* a1, const float* a2, const float* a3, const float* a4,
    const int*& ei, const float*& ea) {
  switch (r) {
    case 0: ei = e0; ea = a0; break;
    case 1: ei = e1; ea = a1; break;
    case 2: ei = e2; ea = a2; break;
    case 3: ei = e3; ea = a3; break;
    default: ei = e4; ea = a4; break;
  }
}

// 1) prep + degree pass (independent work split by blockIdx):
//    b<16      : weight-collapse PARTIALS -> atomicAdd Mv (z pre-scaled log2e, h 2*log2e)
//    b==16     : softmax(att)
//    17<=b<152 : W1 -> bf16 MFMA-B frags; W2 -> W2t
//    b>=152    : deg[rn] += w
__global__ void k_prep_deg(
    const float* __restrict__ Wc_z, const float* __restrict__ bc_z,
    const float* __restrict__ Wl_z, const float* __restrict__ bl_z,
    const float* __restrict__ Wc_h, const float* __restrict__ bc_h,
    const float* __restrict__ Wl_h, const float* __restrict__ bl_h,
    const float* __restrict__ att, const float* __restrict__ W1,
    const float* __restrict__ W2,
    const int* __restrict__ e0, const int* __restrict__ e1,
    const int* __restrict__ e2, const int* __restrict__ e3,
    const int* __restrict__ e4,
    const float* __restrict__ a0, const float* __restrict__ a1,
    const float* __restrict__ a2, const float* __restrict__ a3,
    const float* __restrict__ a4,
    float* __restrict__ Mv, short* __restrict__ Wp, float* __restrict__ W2t,
    float* __restrict__ deg) {
  int b = blockIdx.x, tid = threadIdx.x;
  if (b < 16) {
    int g  = b >> 3;
    int ch = b & 7;
    int k  = tid;
    const float* Wc = g ? Wc_h : Wc_z;
    const float* bc = g ? bc_h : bc_z;
    const float* Wl = g ? Wl_h : Wl_z;
    const float* bl = g ? bl_h : bl_z;
    float scale = g ? 2.0f * LOG2E : LOG2E;
    float m0 = 0.f, m1 = 0.f, m2 = 0.f, m3 = 0.f;
    float v = (ch == 0) ? bl[k] : 0.0f;
    int c0 = ch * 32;
    for (int c = c0; c < c0 + 32; c++) {
      float wl = Wl[c * C + k];
      m0 = fmaf(Wc[0 * C + c], wl, m0);
      m1 = fmaf(Wc[1 * C + c], wl, m1);
      m2 = fmaf(Wc[2 * C + c], wl, m2);
      m3 = fmaf(Wc[3 * C + c], wl, m3);
      v  = fmaf(bc[c], wl, v);
    }
    float* o = Mv + g * (5 * C);
    atomicAdd(&o[0 * C + k], scale * m0);
    atomicAdd(&o[1 * C + k], scale * m1);
    atomicAdd(&o[2 * C + k], scale * m2);
    atomicAdd(&o[3 * C + k], scale * m3);
    atomicAdd(&o[4 * C + k], scale * v);
    return;
  }
  if (b == 16) {
    if (tid < T) {
      float amax = -3.0e38f;
      for (int t = 0; t < T; t++) amax = fmaxf(amax, att[t]);
      float s = 0.f;
      for (int t = 0; t < T; t++) s += __expf(att[t] - amax);
      Mv[10 * C + tid] = __expf(att[tid] - amax) / s;
    }
    return;
  }
  if (b < 152) {
    int idx = (b - 17) * 256 + tid;
    if (idx < 32768) {
      int j    = idx & 7;
      int lane = (idx >> 3) & 63;
      int ch   = (idx >> 9) & 7;
      int kt   = idx >> 12;
      int cin  = ch * 32 + (lane >> 4) * 8 + j;   // K index
      int kout = kt * 16 + (lane & 15);           // N index
      Wp[idx] = f2bf(W1[cin * HIDN + kout]);
    } else if (idx < 32768 + 1536) {
      int r = idx - 32768;
      int o = r >> 7, k = r & 127;
      W2t[r] = W2[k * OUTD + o];
    }
    return;
  }
  int i = (b - 152) * 256 + tid;
  if (i >= EDGE_TOT) return;
  int r = i / ER;
  int e = i - r * ER;
  const int* ei; const float* ea;
  pick_region(r, e0, e1, e2, e3, e4, a0, a1, a2, a3, a4, ei, ea);
  atomicAdd(&deg[r * N + ei[ER + e]], ea[e]);
}

// 2) fill pass (deg final): combined per-node bucket gets (src, coef)
__global__ void k_fill(const int* __restrict__ e0, const int* __restrict__ e1,
                       const int* __restrict__ e2, const int* __restrict__ e3,
                       const int* __restrict__ e4,
                       const float* __restrict__ a0, const float* __restrict__ a1,
                       const float* __restrict__ a2, const float* __restrict__ a3,
                       const float* __restrict__ a4,
                       const float* __restrict__ deg, int* __restrict__ cnt,
                       int2* __restrict__ bucket) {
  int i = blockIdx.x * blockDim.x + threadIdx.x;
  if (i >= EDGE_TOT) return;
  int r = i / ER;
  int e = i - r * ER;
  const int* ei; const float* ea;
  pick_region(r, e0, e1, e2, e3, e4, a0, a1, a2, a3, a4, ei, ea);
  int src = ei[e];
  int dst = ei[ER + e];
  float cf = rsqrtf(deg[r * N + src] + 1.0f) * ea[e] * rsqrtf(deg[r * N + dst] + 1.0f);
  int slot = atomicAdd(&cnt[dst], 1);
  if (slot < CAP) bucket[dst * CAP + slot] = make_int2(src, __float_as_int(cf));
}

// 3) fused gather + gates + attention pooling + MLP.  Block = 16 nodes, 4 waves.
//    Gather: wave w loads nodes w*4..+4 into LDS xs (lane = feature q; bucket
//    row preloaded once, (src,coef) broadcast via __shfl).  One barrier.
//    Gates: wave w owns half (w&1) of all 16 nodes, lane owns 2 channels
//    (VGPR-lean, R11-verified math in packed float2 form).  fp32 h -> global,
//    bf16 relu(h) -> LDS.  One barrier.  16 MFMAs/wave layer-1 + tiny layer-2.
__global__ __launch_bounds__(256) void k_fused(
    const float* __restrict__ x, const float* __restrict__ deg,
    const int* __restrict__ cnt, const int2* __restrict__ bucket,
    const float* __restrict__ Mv, const short* __restrict__ Wp,
    const float* __restrict__ b1, const float* __restrict__ W2t,
    const float* __restrict__ b2,
    float* __restrict__ y_out, float* __restrict__ h_out) {
  __shared__ float xs[16][NFT];       // gathered features (rows 192B, 16B-aligned)
  __shared__ short hs[16][264];       // bf16 relu(h), pad 256->264
  __shared__ float y1s[16][132];      // fp32 layer-1 out, pad 128->132
  int tid = threadIdx.x;
  int wave = tid >> 6, lane = tid & 63;
  int n0 = blockIdx.x * 16;

  // ---- gather phase: 4 nodes per wave, lane = feature q ----
  {
    int q = lane < NFT ? lane : NFT - 1;
    for (int nl = 0; nl < 4; nl++) {
      int rl = wave * 4 + nl;
      int n = n0 + rl;
      float s = 0.f;
#pragma unroll
      for (int r = 0; r < 5; r++) s += 1.0f / (deg[r * N + n] + 1.0f);
      float facc = s * x[n * NFT + q];
      int cv = cnt[n];
      if (cv > CAP) cv = CAP;
      int2 mreg = bucket[n * CAP + (lane & (CAP - 1))];  // slots in lanes 0..31
      for (int j = 0; j < cv; j++) {
        int   src = __shfl(mreg.x, j);
        float cf  = __int_as_float(__shfl(mreg.y, j));
        facc = fmaf(cf, x[src * NFT + q], facc);
      }
      if (lane < NFT) xs[rl][lane] = facc;
    }
  }
  __syncthreads();

  // ---- gates phase: half = wave&1, nodes (wave>>1)*8..+8, 2 ch/lane ----
  {
    int half = wave & 1;
    int nb   = (wave >> 1) * 8;
    int c0 = half * 128 + (lane << 1);
    const float* Mz = Mv;               // pre-scaled by log2e
    const float* Mh = Mv + 5 * C;       // pre-scaled by 2*log2e
    floatx2 mz[4], mh[4], vz, vh;
#pragma unroll
    for (int f = 0; f < 4; f++) {
      mz[f] = *(const floatx2*)(Mz + f * C + c0);
      mh[f] = *(const floatx2*)(Mh + f * C + c0);
    }
    vz = *(const floatx2*)(Mz + 4 * C + c0);
    vh = *(const floatx2*)(Mh + 4 * C + c0);

#pragma unroll
    for (int nl = 0; nl < 8; nl++) {
      int rl = nb + nl;                  // local node 0..15
      int n = n0 + rl;
      const float* xr = &xs[rl][0];      // LDS, broadcast reads
      floatx2 acc = {0.f, 0.f};
#pragma unroll
      for (int tb = 0; tb < 3; tb++) {
        float4 xf0 = *(const float4*)(xr + 0 * T + tb * 4);
        float4 xf1 = *(const float4*)(xr + 1 * T + tb * 4);
        float4 xf2 = *(const float4*)(xr + 2 * T + tb * 4);
        float4 xf3 = *(const float4*)(xr + 3 * T + tb * 4);
        float xs0[4] = {xf0.x, xf0.y, xf0.z, xf0.w};
        float xs1[4] = {xf1.x, xf1.y, xf1.z, xf1.w};
        float xs2[4] = {xf2.x, xf2.y, xf2.z, xf2.w};
        float xs3[4] = {xf3.x, xf3.y, xf3.z, xf3.w};
#pragma unroll
        for (int tt = 0; tt < 4; tt++) {
          int t = tb * 4 + tt;
          float p = Mv[10 * C + t];      // uniform address -> s_load
          floatx2 x0 = {xs0[tt], xs0[tt]};
          floatx2 x1 = {xs1[tt], xs1[tt]};
          floatx2 x2 = {xs2[tt], xs2[tt]};
          floatx2 x3 = {xs3[tt], xs3[tt]};
          floatx2 az = pk_fma(mz[0], x0, pk_fma(mz[1], x1, pk_fma(mz[2], x2, pk_fma(mz[3], x3, vz))));
          floatx2 ah = pk_fma(mh[0], x0, pk_fma(mh[1], x1, pk_fma(mh[2], x2, pk_fma(mh[3], x3, vh))));
          floatx2 e1, e2;
          e1.x = EXP2(az.x); e1.y = EXP2(az.y);        // e^{az_true}
          e2.x = EXP2(ah.x); e2.y = EXP2(ah.y);        // e^{2*ah_true}
          floatx2 one = {1.f, 1.f};
          floatx2 d1 = e1 + one;
          floatx2 d2 = e2 + one;
          floatx2 rD;
          rD.x = __builtin_amdgcn_rcpf(d1.x * d2.x);
          rD.y = __builtin_amdgcn_rcpf(d1.y * d2.y);
          floatx2 pv = {p, p};
          floatx2 pn = pk_fma(pv, e2, -pv);            // p*(e2-1)
          acc = pk_fma(pn, rD, acc);
        }
      }
      float2 o = {acc.x, acc.y};
      *(float2*)(h_out + n * C + c0) = o;               // required fp32 output
      unsigned pk = (unsigned short)f2bf(fmaxf(acc.x, 0.f)) |
                    ((unsigned)(unsigned short)f2bf(fmaxf(acc.y, 0.f)) << 16);
      *(unsigned*)&hs[rl][c0] = pk;                     // bf16 relu(h) -> LDS
    }
  }
  __syncthreads();

  // ---- layer 1: 16 MFMAs per wave (kt = wave*2, wave*2+1) ----
  {
    int quad = lane >> 4, col = lane & 15;
    floatx4 acc2[2];
    acc2[0] = {0.f, 0.f, 0.f, 0.f};
    acc2[1] = {0.f, 0.f, 0.f, 0.f};
#pragma unroll
    for (int ch = 0; ch < 8; ch++) {
      short8 a = *(const short8*)&hs[col][ch * 32 + quad * 8];
#pragma unroll
      for (int kk = 0; kk < 2; kk++) {
        short8 bb = ((const short8*)Wp)[((wave * 2 + kk) * 8 + ch) * 64 + lane];
        acc2[kk] = __builtin_amdgcn_mfma_f32_16x16x32_bf16(a, bb, acc2[kk], 0, 0, 0);
      }
    }
#pragma unroll
    for (int kk = 0; kk < 2; kk++) {
      int kt = wave * 2 + kk;
      float bias = b1[kt * 16 + col];
#pragma unroll
      for (int r = 0; r < 4; r++)
        y1s[quad * 4 + r][kt * 16 + col] = fmaxf(acc2[kk][r] + bias, 0.f);
    }
  }
  __syncthreads();

  // ---- layer 2: 16 nodes x 12 outputs = 192 threads ----
  if (tid < 16 * OUTD) {
    int nl = tid / OUTD, o = tid - nl * OUTD;
    float sacc = b2[o];
    const float* yr = &y1s[nl][0];
    const float* wr = W2t + o * HIDN;
#pragma unroll 8
    for (int k4 = 0; k4 < 32; k4++) {
      float4 yv = *(const float4*)(yr + 4 * k4);
      float4 wv = *(const float4*)(wr + 4 * k4);
      sacc = fmaf(yv.x, wv.x, fmaf(yv.y, wv.y, fmaf(yv.z, wv.z, fmaf(yv.w, wv.w, sacc))));
    }
    y_out[(n0 + nl) * OUTD + o] = sacc;
  }
}

extern "C" void kernel_launch(void* const* d_in, const int* in_sizes, int n_in,
                              void* d_out, int out_size, void* d_ws, size_t ws_size,
                              hipStream_t stream) {
  const float* x   = (const float*)d_in[0];
  // d_in[1] full-graph edge_index: provably unused
  const int* eIA = (const int*)d_in[2];
  const int* eKS = (const int*)d_in[3];
  const int* eKY = (const int*)d_in[4];
  const int* eOH = (const int*)d_in[5];
  const int* eWI = (const int*)d_in[6];
  const float* aIA = (const float*)d_in[7];
  const float* aKS = (const float*)d_in[8];
  const float* aKY = (const float*)d_in[9];
  const float* aOH = (const float*)d_in[10];
  const float* aWI = (const float*)d_in[11];
  const float* Wc_z = (const float*)d_in[12];
  const float* bc_z = (const float*)d_in[13];
  const float* Wl_z = (const float*)d_in[14];
  const float* bl_z = (const float*)d_in[15];
  // r-gate params (16..19) cannot influence the output (H=0)
  const float* Wc_h = (const float*)d_in[20];
  const float* bc_h = (const float*)d_in[21];
  const float* Wl_h = (const float*)d_in[22];
  const float* bl_h = (const float*)d_in[23];
  const float* att  = (const float*)d_in[24];
  const float* W1   = (const float*)d_in[25];
  const float* b1   = (const float*)d_in[26];
  const float* W2   = (const float*)d_in[27];
  const float* b2   = (const float*)d_in[28];

  float* ws     = (float*)d_ws;
  float* deg    = ws + WS_DEG;
  int*   cnt    = (int*)(ws + WS_CNT);
  float* Mv     = ws + WS_MV;
  short* Wp     = (short*)(ws + WS_WP);
  float* W2t    = ws + WS_W2T;
  int2*  bucket = (int2*)(ws + WS_BUCKET);

  float* y_out = (float*)d_out;            // [N,12]
  float* h_out = y_out + N * OUTD;         // [N,256]

  hipMemsetAsync(deg, 0, WS_ZEND * sizeof(float), stream);  // deg + cnt + Mv

  k_prep_deg<<<152 + EB, 256, 0, stream>>>(Wc_z, bc_z, Wl_z, bl_z,
                                           Wc_h, bc_h, Wl_h, bl_h,
                                           att, W1, W2,
                                           eIA, eKS, eKY, eOH, eWI,
                                           aIA, aKS, aKY, aOH, aWI,
                                           Mv, Wp, W2t, deg);
  k_fill<<<EB, 256, 0, stream>>>(eIA, eKS, eKY, eOH, eWI,
                                 aIA, aKS, aKY, aOH, aWI,
                                 deg, cnt, bucket);
  k_fused<<<N / 16, 256, 0, stream>>>(x, deg, cnt, bucket, Mv, Wp, b1, W2t, b2,
                                      y_out, h_out);
}